// Round 2
// baseline (221.376 us; speedup 1.0000x reference)
//
#include <hip/hip_runtime.h>
#include <hip/hip_bf16.h>
#include <math.h>

typedef __attribute__((ext_vector_type(4))) float f32x4;
typedef __attribute__((ext_vector_type(8))) short s16x8;
typedef __attribute__((ext_vector_type(4))) short s16x4;

#define NB 8
#define NT 2048
#define NC 1024
#define NH 128
// log2(e)/sqrt(C) folded into Q at projection time (exp2-domain softmax)
#define QSCALE 0.04508422002778f

__device__ __forceinline__ short f2bf(float f) {
  union { float f; unsigned u; } v; v.f = f;
  unsigned r = v.u + 0x7fffu + ((v.u >> 16) & 1u);
  return (short)(r >> 16);
}

__device__ __forceinline__ void glds16(const short* g, short* l) {
  __builtin_amdgcn_global_load_lds(
      (const __attribute__((address_space(1))) unsigned int*)g,
      (__attribute__((address_space(3))) unsigned int*)l, 16, 0, 0);
}

// ---------------- kernel 0: W [C][H] fp32 -> Wt [3][H][C] bf16 --------------
// Coalesced 64x64 LDS-transpose tiles. grid (16 k-tiles, 2 n-tiles, 3 projs).
__global__ __launch_bounds__(256)
void wt_kernel(const float* __restrict__ Wq, const float* __restrict__ Wk,
               const float* __restrict__ Wv, short* __restrict__ Wt) {
  __shared__ short T[64 * 72];
  const int tid = threadIdx.x;
  const int k0 = blockIdx.x * 64, n0 = blockIdx.y * 64, proj = blockIdx.z;
  const float* W = (proj == 0) ? Wq : ((proj == 1) ? Wk : Wv);
#pragma unroll
  for (int u = 0; u < 4; u++) {
    int row = u * 16 + (tid >> 4);      // k within tile
    int col4 = (tid & 15) * 4;          // n within tile
    float4 v = *(const float4*)(W + (size_t)(k0 + row) * NH + n0 + col4);
    T[(col4 + 0) * 72 + row] = f2bf(v.x);
    T[(col4 + 1) * 72 + row] = f2bf(v.y);
    T[(col4 + 2) * 72 + row] = f2bf(v.z);
    T[(col4 + 3) * 72 + row] = f2bf(v.w);
  }
  __syncthreads();
#pragma unroll
  for (int u = 0; u < 2; u++) {
    int c = tid + 256 * u;              // 0..511
    int n = c >> 3, c8 = c & 7;
    s16x8 v = *(const s16x8*)(T + n * 72 + c8 * 8);
    *(s16x8*)(Wt + (size_t)proj * (NH * NC) + (size_t)(n0 + n) * NC + k0 + c8 * 8) = v;
  }
}

// ---------------- kernel 1: QKV projection ---------------------------------
// 768 blocks (xcd-swizzled: proj = orig>>8, mtile = orig&255), 256 thr, M=64.
// LDS: A[2][64][64] + B[2][128][64] bf16, XOR-swizzled (c8 ^= row&7 on 16B
// chunks). B staged via global_load_lds w/ pre-swizzled source; A reg-staged
// (fp32->bf16 cvt) with issue-early/write-late split. Double-buffered.
__global__ __launch_bounds__(256, 3)
void proj_kernel(const float* __restrict__ x, const short* __restrict__ Wt,
                 const float* __restrict__ bq, const float* __restrict__ bk,
                 const float* __restrict__ bv,
                 short* __restrict__ Qb, short* __restrict__ Kb, short* __restrict__ Vtb) {
  __shared__ __align__(16) short smem[2 * 12288];  // 48 KiB: per buf: A 4096 + B 8192

  const int tid = threadIdx.x;
  const int w = tid >> 6, lane = tid & 63;
  const int lr = lane & 15, lg = lane >> 4;

  const int bid = blockIdx.x;
  const int orig = (bid & 7) * 96 + (bid >> 3);  // bijective, same-proj -> same XCD
  const int proj = orig >> 8;
  const int m0 = (orig & 255) * 64;

  const short* Wtp = Wt + (size_t)proj * (NH * NC);

  f32x4 acc[8];
#pragma unroll
  for (int i = 0; i < 8; i++) acc[i] = {0.f, 0.f, 0.f, 0.f};

  const int s0 = 2 * tid, s1 = 2 * tid + 1;
  const int ar0 = s0 >> 3, ac0 = s0 & 7, ar1 = s1 >> 3, ac1 = s1 & 7;
  const float* asrc0base = x + (size_t)(m0 + ar0) * NC + ((ac0 ^ (ar0 & 7)) * 8);
  const float* asrc1base = x + (size_t)(m0 + ar1) * NC + ((ac1 ^ (ar1 & 7)) * 8);

  float4 a00, a01, a10, a11;

  // ---- staging helpers (inlined by macro-ish lambdas) ----
  auto stageA_load = [&](int k0) {
    a00 = *(const float4*)(asrc0base + k0);
    a01 = *(const float4*)(asrc0base + k0 + 4);
    a10 = *(const float4*)(asrc1base + k0);
    a11 = *(const float4*)(asrc1base + k0 + 4);
  };
  auto stageA_write = [&](int buf) {
    s16x8 v;
    v[0] = f2bf(a00.x); v[1] = f2bf(a00.y); v[2] = f2bf(a00.z); v[3] = f2bf(a00.w);
    v[4] = f2bf(a01.x); v[5] = f2bf(a01.y); v[6] = f2bf(a01.z); v[7] = f2bf(a01.w);
    *(s16x8*)(smem + buf * 12288 + s0 * 8) = v;
    v[0] = f2bf(a10.x); v[1] = f2bf(a10.y); v[2] = f2bf(a10.z); v[3] = f2bf(a10.w);
    v[4] = f2bf(a11.x); v[5] = f2bf(a11.y); v[6] = f2bf(a11.z); v[7] = f2bf(a11.w);
    *(s16x8*)(smem + buf * 12288 + s1 * 8) = v;
  };
  auto stageB = [&](int buf, int k0) {
#pragma unroll
    for (int u = 0; u < 4; u++) {
      int g = w * 4 + u;              // 16 groups of 64 slots
      int s = g * 64 + lane;
      int n = s >> 3, c8 = s & 7;
      const short* src = Wtp + (size_t)n * NC + k0 + ((c8 ^ (n & 7)) * 8);
      short* dst = smem + buf * 12288 + 4096 + g * 512;  // wave-uniform base
      glds16(src, dst);
    }
  };

  // prologue
  stageA_load(0);
  stageB(0, 0);
  stageA_write(0);
  __syncthreads();

  for (int it = 0; it < 16; ++it) {
    int buf = it & 1, nb = buf ^ 1;
    if (it < 15) { stageA_load((it + 1) * 64); stageB(nb, (it + 1) * 64); }
    // compute on buf
    const short* A = smem + buf * 12288;
    const short* B = smem + buf * 12288 + 4096;
    const int arow = w * 16 + lr;
#pragma unroll
    for (int kc = 0; kc < 2; kc++) {
      s16x8 af = *(const s16x8*)(A + arow * 64 + (((kc * 4 + lg) ^ (arow & 7)) * 8));
#pragma unroll
      for (int ni = 0; ni < 8; ni++) {
        int brow = ni * 16 + lr;
        s16x8 bf = *(const s16x8*)(B + brow * 64 + (((kc * 4 + lg) ^ (brow & 7)) * 8));
        acc[ni] = __builtin_amdgcn_mfma_f32_16x16x32_bf16(af, bf, acc[ni], 0, 0, 0);
      }
    }
    if (it < 15) stageA_write(nb);
    __syncthreads();
  }

  const float* bias = (proj == 0) ? bq : ((proj == 1) ? bk : bv);
  const float scl = (proj == 0) ? QSCALE : 1.0f;
  short* Tr = smem;  // reuse

  if (proj < 2) {
    // Tr[t][d] (t 0..63, stride 136), coalesced row-major out
#pragma unroll
    for (int ni = 0; ni < 8; ni++) {
      float bn = bias[ni * 16 + lr];
#pragma unroll
      for (int r = 0; r < 4; r++) {
        int t = w * 16 + lg * 4 + r;
        Tr[t * 136 + ni * 16 + lr] = f2bf((acc[ni][r] + bn) * scl);
      }
    }
    __syncthreads();
    short* dst = (proj == 0) ? Qb : Kb;
#pragma unroll
    for (int i = 0; i < 4; i++) {
      int c = tid + 256 * i;  // 0..1023
      int t = c >> 4, c8 = c & 15;
      s16x8 v = *(const s16x8*)(Tr + t * 136 + c8 * 8);
      *(s16x8*)(dst + (size_t)(m0 + t) * NH + c8 * 8) = v;
    }
  } else {
    // Tr2[d][t] (d 0..127, stride 72) -> Vt[b][d][t]
#pragma unroll
    for (int ni = 0; ni < 8; ni++) {
      float bn = bias[ni * 16 + lr];
      int d = ni * 16 + lr;
      int t = w * 16 + lg * 4;
      s16x4 v;
      v[0] = f2bf(acc[ni][0] + bn);
      v[1] = f2bf(acc[ni][1] + bn);
      v[2] = f2bf(acc[ni][2] + bn);
      v[3] = f2bf(acc[ni][3] + bn);
      *(s16x4*)(Tr + d * 72 + t) = v;
    }
    __syncthreads();
    int b = m0 >> 11, t0 = m0 & 2047;
#pragma unroll
    for (int i = 0; i < 4; i++) {
      int c = tid + 256 * i;  // 0..1023
      int d = c >> 3, c8 = c & 7;
      s16x8 v = *(const s16x8*)(Tr + d * 72 + c8 * 8);
      *(s16x8*)(Vtb + (size_t)b * (NH * NT) + (size_t)d * NT + t0 + c8 * 8) = v;
    }
  }
}

// ---------------- kernel 2: causal flash attention (streaming, no staging) --
// 512 blocks x 4 waves. Block handles q-tiles (j, 127-j) of 16 rows (balanced:
// ~17 kv-32-tile iters total). Within a phase, wave w processes kv tiles
// t ≡ w (mod 4) fully independently (K/V frags read direct from L2 — no
// sharing, so LDS staging would be pure overhead). End-of-phase 4-way combine
// via LDS. XCD swizzle: batch b -> XCD b (Q/K/V ~1.5MB, L2-resident).
__global__ __launch_bounds__(256, 3)
void attn_kernel(const short* __restrict__ Qb, const short* __restrict__ Kb,
                 const short* __restrict__ Vtb, float* __restrict__ out) {
  __shared__ float Cb[3][16][132];
  __shared__ float2 Ml[3][16];

  const int tid = threadIdx.x;
  const int w = tid >> 6, lane = tid & 63;
  const int lr = lane & 15, lg = lane >> 4;

  const int bid = blockIdx.x;
  const int orig = (bid & 7) * 64 + (bid >> 3);  // batch -> XCD
  const int batch = orig >> 6;
  const int pairid = orig & 63;

  const short* Kp = Kb + (size_t)batch * NT * NH;
  const short* Vp = Vtb + (size_t)batch * NH * NT;

#pragma unroll 1
  for (int ph = 0; ph < 2; ph++) {
    const int j = ph ? (127 - pairid) : pairid;
    const int q0 = j * 16;
    const int q = q0 + lr;

    const short* Qrow = Qb + (size_t)(batch * NT + q) * NH;
    s16x8 qf[4];
#pragma unroll
    for (int dc = 0; dc < 4; dc++) qf[dc] = *(const s16x8*)(Qrow + dc * 32 + lg * 8);

    f32x4 acc[8];
#pragma unroll
    for (int i = 0; i < 8; i++) acc[i] = {0.f, 0.f, 0.f, 0.f};
    float m_run = -3.0e38f, l_run = 0.f;

    const int Nt = (q0 + 47) >> 5;  // kv-32 tiles needed

    for (int t = w; t < Nt; t += 4) {
      const int kv0 = t * 32;
      // S^T = K * Q^T over this 32-kv tile
      f32x4 st0 = {0.f, 0.f, 0.f, 0.f}, st1 = st0;
      const short* Kt = Kp + (size_t)(kv0 + lr) * NH + lg * 8;
#pragma unroll
      for (int dc = 0; dc < 4; dc++) {
        s16x8 k0f = *(const s16x8*)(Kt + dc * 32);
        s16x8 k1f = *(const s16x8*)(Kt + 16 * NH + dc * 32);
        st0 = __builtin_amdgcn_mfma_f32_16x16x32_bf16(k0f, qf[dc], st0, 0, 0, 0);
        st1 = __builtin_amdgcn_mfma_f32_16x16x32_bf16(k1f, qf[dc], st1, 0, 0, 0);
      }
      if (kv0 + 31 > q0) {  // causal mask (diagonal tiles)
#pragma unroll
        for (int r = 0; r < 4; r++) {
          if (kv0 + lg * 4 + r > q) st0[r] = -3.0e38f;
          if (kv0 + 16 + lg * 4 + r > q) st1[r] = -3.0e38f;
        }
      }
      // online softmax (exp2-domain), reduce over lanes {l, l^16, l^32, l^48}
      float tm = -3.0e38f;
#pragma unroll
      for (int r = 0; r < 4; r++) { tm = fmaxf(tm, st0[r]); tm = fmaxf(tm, st1[r]); }
      tm = fmaxf(tm, __shfl_xor(tm, 16, 64));
      tm = fmaxf(tm, __shfl_xor(tm, 32, 64));
      float m_new = fmaxf(m_run, tm);
      float corr = exp2f(m_run - m_new);
      float psum = 0.f;
      s16x8 pf;
#pragma unroll
      for (int r = 0; r < 4; r++) {
        float p0 = exp2f(st0[r] - m_new);
        float p1 = exp2f(st1[r] - m_new);
        psum += p0 + p1;
        pf[r] = f2bf(p0);
        pf[4 + r] = f2bf(p1);
      }
      psum += __shfl_xor(psum, 16, 64);
      psum += __shfl_xor(psum, 32, 64);
      l_run = l_run * corr + psum;
      m_run = m_new;
#pragma unroll
      for (int i = 0; i < 8; i++) acc[i] *= corr;
      // O^T += Vt * P^T  (permuted k-slot mapping: slot r -> k=4lg+r, 4+r -> 16+4lg+r)
#pragma unroll
      for (int dm = 0; dm < 8; dm++) {
        const short* vp = Vp + (size_t)(dm * 16 + lr) * NT + kv0 + lg * 4;
        s16x4 v0 = *(const s16x4*)vp;
        s16x4 v1 = *(const s16x4*)(vp + 16);
        s16x8 vf = __builtin_shufflevector(v0, v1, 0, 1, 2, 3, 4, 5, 6, 7);
        acc[dm] = __builtin_amdgcn_mfma_f32_16x16x32_bf16(vf, pf, acc[dm], 0, 0, 0);
      }
    }

    __syncthreads();
    if (w > 0) {
#pragma unroll
      for (int dm = 0; dm < 8; dm++)
        *(f32x4*)&Cb[w - 1][lr][dm * 16 + lg * 4] = acc[dm];
      if (lg == 0) Ml[w - 1][lr] = make_float2(m_run, l_run);
    }
    __syncthreads();
    if (w == 0) {
      float2 ml0 = Ml[0][lr], ml1 = Ml[1][lr], ml2 = Ml[2][lr];
      float M = fmaxf(fmaxf(m_run, ml0.x), fmaxf(ml1.x, ml2.x));
      float c0 = exp2f(m_run - M);
      float c1 = exp2f(ml0.x - M);
      float c2 = exp2f(ml1.x - M);
      float c3 = exp2f(ml2.x - M);
      float lt = l_run * c0 + ml0.y * c1 + ml1.y * c2 + ml2.y * c3;
      float inv = 1.0f / lt;
      float* orow = out + (size_t)(batch * NT + q) * NH;
#pragma unroll
      for (int dm = 0; dm < 8; dm++) {
        f32x4 v = acc[dm] * c0;
        v += (*(const f32x4*)&Cb[0][lr][dm * 16 + lg * 4]) * c1;
        v += (*(const f32x4*)&Cb[1][lr][dm * 16 + lg * 4]) * c2;
        v += (*(const f32x4*)&Cb[2][lr][dm * 16 + lg * 4]) * c3;
        v *= inv;
        *(f32x4*)(orow + dm * 16 + lg * 4) = v;
      }
    }
    __syncthreads();
  }
}

// ---------------- launch ----------------------------------------------------
extern "C" void kernel_launch(void* const* d_in, const int* in_sizes, int n_in,
                              void* d_out, int out_size, void* d_ws, size_t ws_size,
                              hipStream_t stream) {
  const float* x = (const float*)d_in[0];
  const float* Wq = (const float*)d_in[1];
  const float* bq = (const float*)d_in[2];
  const float* Wk = (const float*)d_in[3];
  const float* bk = (const float*)d_in[4];
  const float* Wv = (const float*)d_in[5];
  const float* bv = (const float*)d_in[6];
  float* out = (float*)d_out;

  char* ws = (char*)d_ws;
  short* Wt = (short*)ws;                            // 786432 B
  short* Qb = (short*)(ws + 786432);                 // 4 MiB
  short* Kb = (short*)(ws + 786432 + 4194304);       // 4 MiB
  short* Vtb = (short*)(ws + 786432 + 2 * 4194304);  // 4 MiB

  wt_kernel<<<dim3(16, 2, 3), dim3(256), 0, stream>>>(Wq, Wk, Wv, Wt);
  proj_kernel<<<dim3(768), dim3(256), 0, stream>>>(x, Wt, bq, bk, bv, Qb, Kb, Vtb);
  attn_kernel<<<dim3(512), dim3(256), 0, stream>>>(Qb, Kb, Vtb, out);
}

// Round 4
// 206.591 us; speedup vs baseline: 1.0716x; 1.0716x over previous
//
#include <hip/hip_runtime.h>
#include <hip/hip_bf16.h>
#include <math.h>

typedef __attribute__((ext_vector_type(4))) float f32x4;
typedef __attribute__((ext_vector_type(8))) short s16x8;
typedef __attribute__((ext_vector_type(4))) short s16x4;

#define NB 8
#define NT 2048
#define NC 1024
#define NH 128
// log2(e)/sqrt(C) folded into Q at projection time (exp2-domain softmax)
#define QSCALE 0.04508422002778f
#define PIECES 80   // per batch: sum_j ceil((j+1)/8), j=0..31 (KVCHUNK=512, qtile=64)

__device__ __forceinline__ short f2bf(float f) {
  union { float f; unsigned u; } v; v.f = f;
  unsigned r = v.u + 0x7fffu + ((v.u >> 16) & 1u);
  return (short)(r >> 16);
}

__device__ __forceinline__ void glds16(const short* g, short* l) {
  __builtin_amdgcn_global_load_lds(
      (const __attribute__((address_space(1))) unsigned int*)g,
      (__attribute__((address_space(3))) unsigned int*)l, 16, 0, 0);
}

// ---------------- kernel 0: W [C][H] fp32 -> Wt [3][H][C] bf16 --------------
__global__ __launch_bounds__(256)
void wt_kernel(const float* __restrict__ Wq, const float* __restrict__ Wk,
               const float* __restrict__ Wv, short* __restrict__ Wt) {
  __shared__ short T[64 * 72];
  const int tid = threadIdx.x;
  const int k0 = blockIdx.x * 64, n0 = blockIdx.y * 64, proj = blockIdx.z;
  const float* W = (proj == 0) ? Wq : ((proj == 1) ? Wk : Wv);
#pragma unroll
  for (int u = 0; u < 4; u++) {
    int row = u * 16 + (tid >> 4);
    int col4 = (tid & 15) * 4;
    float4 v = *(const float4*)(W + (size_t)(k0 + row) * NH + n0 + col4);
    T[(col4 + 0) * 72 + row] = f2bf(v.x);
    T[(col4 + 1) * 72 + row] = f2bf(v.y);
    T[(col4 + 2) * 72 + row] = f2bf(v.z);
    T[(col4 + 3) * 72 + row] = f2bf(v.w);
  }
  __syncthreads();
#pragma unroll
  for (int u = 0; u < 2; u++) {
    int c = tid + 256 * u;
    int n = c >> 3, c8 = c & 7;
    s16x8 v = *(const s16x8*)(T + n * 72 + c8 * 8);
    *(s16x8*)(Wt + (size_t)proj * (NH * NC) + (size_t)(n0 + n) * NC + k0 + c8 * 8) = v;
  }
}

// ---------------- kernel 1: QKV projection, m97-style 128x128 tile ---------
// grid (3 projs, 128 m-tiles), 256 thr (4 waves, 2x2 wave grid of 64x64).
// LDS single-buffer A[128][64]+B[128][64] bf16, XOR-swizzled 16B chunks
// (chunk ^= row&7). B via global_load_lds (swizzle folded into source addr —
// within-cacheline permute). A reg-prefetched one K-step ahead (T14).
__global__ __launch_bounds__(256)
void proj_kernel(const float* __restrict__ x, const short* __restrict__ Wt,
                 const float* __restrict__ bq, const float* __restrict__ bk,
                 const float* __restrict__ bv,
                 short* __restrict__ Qb, short* __restrict__ Kb, short* __restrict__ Vtb) {
  __shared__ __align__(16) short smem[17408];  // A[0..8191], B[8192..16383]; epi: Tr[128][136]
  short* As = smem;
  short* Bs = smem + 8192;

  const int tid = threadIdx.x;
  const int w = tid >> 6, lane = tid & 63;
  const int lr = lane & 15, lg = lane >> 4;
  const int proj = blockIdx.x;
  const int m0 = blockIdx.y * 128;
  const int msub = (w & 1) * 64, nsub = (w >> 1) * 64;

  const short* Wtp = Wt + (size_t)proj * (NH * NC);
  const float* asrc = x + (size_t)(m0 + (tid >> 1)) * NC + (tid & 1) * 32;
  const int arow = tid >> 1;

  f32x4 acc[4][4];
#pragma unroll
  for (int i = 0; i < 4; i++)
#pragma unroll
    for (int j = 0; j < 4; j++) acc[i][j] = {0.f, 0.f, 0.f, 0.f};

  float4 pa[8], pb_[8];
#pragma unroll
  for (int u = 0; u < 8; u++) pa[u] = *(const float4*)(asrc + u * 4);

  auto body = [&](int s, float4 (&cur)[8], float4 (&nxt)[8]) {
    const int k0 = s * 64;
    if (s < 15) {
#pragma unroll
      for (int u = 0; u < 8; u++) nxt[u] = *(const float4*)(asrc + k0 + 64 + u * 4);
    }
    // A: cvt + swizzled ds_write (4 x s16x8)
#pragma unroll
    for (int u = 0; u < 4; u++) {
      float4 a = cur[2 * u], b2 = cur[2 * u + 1];
      s16x8 v;
      v[0] = f2bf(a.x); v[1] = f2bf(a.y); v[2] = f2bf(a.z); v[3] = f2bf(a.w);
      v[4] = f2bf(b2.x); v[5] = f2bf(b2.y); v[6] = f2bf(b2.z); v[7] = f2bf(b2.w);
      int cc = (tid & 1) * 4 + u;
      *(s16x8*)(As + arow * 64 + ((cc ^ (arow & 7)) * 8)) = v;
    }
    // B: glds16, source-swizzled
#pragma unroll
    for (int u = 0; u < 4; u++) {
      int boff = w * 4096 + u * 1024 + lane * 16;
      int n = boff >> 7, cc = (boff >> 4) & 7;
      glds16(Wtp + (size_t)n * NC + k0 + ((cc ^ (n & 7)) * 8), Bs + w * 2048 + u * 512);
    }
    __syncthreads();
#pragma unroll
    for (int kc = 0; kc < 2; kc++) {
      s16x8 af[4], bf[4];
#pragma unroll
      for (int mi = 0; mi < 4; mi++) {
        int row = msub + mi * 16 + lr;
        af[mi] = *(const s16x8*)(As + row * 64 + (((kc * 4 + lg) ^ (lr & 7)) * 8));
      }
#pragma unroll
      for (int ni = 0; ni < 4; ni++) {
        int row = nsub + ni * 16 + lr;
        bf[ni] = *(const s16x8*)(Bs + row * 64 + (((kc * 4 + lg) ^ (lr & 7)) * 8));
      }
#pragma unroll
      for (int mi = 0; mi < 4; mi++)
#pragma unroll
        for (int ni = 0; ni < 4; ni++)
          acc[mi][ni] = __builtin_amdgcn_mfma_f32_16x16x32_bf16(af[mi], bf[ni], acc[mi][ni], 0, 0, 0);
    }
    __syncthreads();
  };

  for (int ss = 0; ss < 8; ss++) { body(2 * ss, pa, pb_); body(2 * ss + 1, pb_, pa); }

  const float* bias = (proj == 0) ? bq : ((proj == 1) ? bk : bv);
  const float scl = (proj == 0) ? QSCALE : 1.0f;
  short* Tr = smem;  // [128][136]

  if (proj < 2) {
#pragma unroll
    for (int mi = 0; mi < 4; mi++)
#pragma unroll
      for (int ni = 0; ni < 4; ni++) {
        float bn = bias[nsub + ni * 16 + lr];
        int d = nsub + ni * 16 + lr;
#pragma unroll
        for (int r = 0; r < 4; r++) {
          int t = msub + mi * 16 + lg * 4 + r;
          Tr[t * 136 + d] = f2bf((acc[mi][ni][r] + bn) * scl);
        }
      }
    __syncthreads();
    short* dst = (proj == 0) ? Qb : Kb;
#pragma unroll
    for (int i = 0; i < 8; i++) {
      int c = tid + 256 * i;  // 0..2047
      int t = c >> 4, cc = c & 15;
      s16x8 v = *(const s16x8*)(Tr + t * 136 + cc * 8);
      *(s16x8*)(dst + (size_t)(m0 + t) * NH + cc * 8) = v;
    }
  } else {
#pragma unroll
    for (int mi = 0; mi < 4; mi++)
#pragma unroll
      for (int ni = 0; ni < 4; ni++) {
        float bn = bias[nsub + ni * 16 + lr];
        int d = nsub + ni * 16 + lr;
        int t0 = msub + mi * 16 + lg * 4;
        s16x4 v;
        v[0] = f2bf(acc[mi][ni][0] + bn);
        v[1] = f2bf(acc[mi][ni][1] + bn);
        v[2] = f2bf(acc[mi][ni][2] + bn);
        v[3] = f2bf(acc[mi][ni][3] + bn);
        *(s16x4*)(Tr + d * 136 + t0) = v;
      }
    __syncthreads();
    int b = m0 >> 11, t0g = m0 & 2047;
#pragma unroll
    for (int i = 0; i < 8; i++) {
      int c = tid + 256 * i;
      int d = c >> 4, cc = c & 15;
      s16x8 v = *(const s16x8*)(Tr + d * 136 + cc * 8);
      *(s16x8*)(Vtb + (size_t)b * (NH * NT) + (size_t)d * NT + t0g + cc * 8) = v;
    }
  }
}

// ---------------- kernel 2: split-KV flash attention partials --------------
// grid (8 batches, 80 pieces). Piece r -> (q-tile j of 64 rows, kv chunk of
// 512). 4 waves x 16 q-rows share double-buffered LDS K/V tiles (KVSTEP=32)
// staged via global_load_lds with source-address XOR swizzle. P==1 pieces
// (j<8) write out directly; others write fp32 partials + (m,l) to ws.
__global__ __launch_bounds__(256)
void attn_partial(const short* __restrict__ Qb, const short* __restrict__ Kb,
                  const short* __restrict__ Vtb, float* __restrict__ out,
                  float* __restrict__ part, float* __restrict__ partml) {
  __shared__ __align__(16) short smem[16384];  // K[2][32][128] @0, V[2][128][32] @8192

  const int tid = threadIdx.x;
  const int w = tid >> 6, lane = tid & 63;
  const int lr = lane & 15, lg = lane >> 4;

  const int batch = blockIdx.x;
  const int r = (PIECES - 1) - blockIdx.y;  // heavy pieces first
  int j = 0, pfx = 0;
  while (pfx + (j >> 3) + 1 <= r) { pfx += (j >> 3) + 1; j++; }
  const int c = r - pfx;
  const int P = (j >> 3) + 1;
  const int q0 = j * 64;
  const int kv_begin = c * 512;
  const int kv_end = min(kv_begin + 512, (j + 1) * 64);
  const int nsteps = (kv_end - kv_begin) >> 5;

  const short* Kp = Kb + (size_t)batch * NT * NH;
  const short* Vp = Vtb + (size_t)batch * NH * NT;
  const int q = q0 + w * 16 + lr;

  const short* Qrow = Qb + (size_t)(batch * NT + q) * NH;
  s16x8 qf[4];
#pragma unroll
  for (int dc = 0; dc < 4; dc++) qf[dc] = *(const s16x8*)(Qrow + dc * 32 + lg * 8);

  f32x4 acc[8];
#pragma unroll
  for (int i = 0; i < 8; i++) acc[i] = {0.f, 0.f, 0.f, 0.f};
  float m_run = -3.0e38f, l_run = 0.f;

  auto stage = [&](int buf, int kv0) {
#pragma unroll
    for (int u = 0; u < 2; u++) {  // K: 8KB tile
      int boff = w * 2048 + u * 1024 + lane * 16;
      int row = boff >> 8, ch = (boff >> 4) & 15;
      int sch = (ch & 8) | ((ch & 7) ^ (row & 7));
      glds16(Kp + (size_t)(kv0 + row) * NH + sch * 8, smem + buf * 4096 + w * 1024 + u * 512);
    }
#pragma unroll
    for (int u = 0; u < 2; u++) {  // V: 8KB tile [128 d][32 t]
      int boff = w * 2048 + u * 1024 + lane * 16;
      int d = boff >> 6, ch = (boff >> 4) & 3;
      int sch = ch ^ (d & 3);
      glds16(Vp + (size_t)d * NT + kv0 + sch * 8, smem + 8192 + buf * 4096 + w * 1024 + u * 512);
    }
  };

  stage(0, kv_begin);
  __syncthreads();

  for (int s = 0; s < nsteps; s++) {
    const int buf = s & 1;
    const int kv0 = kv_begin + s * 32;
    if (s + 1 < nsteps) stage(buf ^ 1, kv0 + 32);

    const short* Kl = smem + buf * 4096;
    const short* Vl = smem + 8192 + buf * 4096;

    f32x4 st0 = {0.f, 0.f, 0.f, 0.f}, st1 = st0;
#pragma unroll
    for (int dc = 0; dc < 4; dc++) {
      int ch = dc * 4 + lg;
      int sch = (ch & 8) | ((ch & 7) ^ (lr & 7));
      s16x8 k0f = *(const s16x8*)(Kl + lr * 128 + sch * 8);
      s16x8 k1f = *(const s16x8*)(Kl + (16 + lr) * 128 + sch * 8);
      st0 = __builtin_amdgcn_mfma_f32_16x16x32_bf16(k0f, qf[dc], st0, 0, 0, 0);
      st1 = __builtin_amdgcn_mfma_f32_16x16x32_bf16(k1f, qf[dc], st1, 0, 0, 0);
    }
    if (kv0 + 31 > q0) {  // diagonal: causal mask
#pragma unroll
      for (int rr = 0; rr < 4; rr++) {
        if (kv0 + lg * 4 + rr > q) st0[rr] = -3.0e38f;
        if (kv0 + 16 + lg * 4 + rr > q) st1[rr] = -3.0e38f;
      }
    }
    float tm = -3.0e38f;
#pragma unroll
    for (int rr = 0; rr < 4; rr++) { tm = fmaxf(tm, st0[rr]); tm = fmaxf(tm, st1[rr]); }
    tm = fmaxf(tm, __shfl_xor(tm, 16, 64));
    tm = fmaxf(tm, __shfl_xor(tm, 32, 64));
    float m_new = fmaxf(m_run, tm);
    float corr = exp2f(m_run - m_new);
    float psum = 0.f;
    s16x8 pf;
#pragma unroll
    for (int rr = 0; rr < 4; rr++) {
      float p0 = exp2f(st0[rr] - m_new);
      float p1 = exp2f(st1[rr] - m_new);
      psum += p0 + p1;
      pf[rr] = f2bf(p0);
      pf[4 + rr] = f2bf(p1);
    }
    psum += __shfl_xor(psum, 16, 64);
    psum += __shfl_xor(psum, 32, 64);
    l_run = l_run * corr + psum;
    m_run = m_new;
#pragma unroll
    for (int i = 0; i < 8; i++) acc[i] *= corr;
#pragma unroll
    for (int dm = 0; dm < 8; dm++) {
      int d = dm * 16 + lr;
      const short* vb = Vl + d * 32;
      int c0 = (lg >> 1) ^ (d & 3);
      int c1 = c0 ^ 2;
      s16x4 v0 = *(const s16x4*)(vb + c0 * 8 + (lg & 1) * 4);
      s16x4 v1 = *(const s16x4*)(vb + c1 * 8 + (lg & 1) * 4);
      s16x8 vf = __builtin_shufflevector(v0, v1, 0, 1, 2, 3, 4, 5, 6, 7);
      acc[dm] = __builtin_amdgcn_mfma_f32_16x16x32_bf16(vf, pf, acc[dm], 0, 0, 0);
    }
    __syncthreads();
  }

  if (P == 1) {
    const float inv = 1.f / l_run;
    float* orow = out + (size_t)(batch * NT + q) * NH;
#pragma unroll
    for (int dm = 0; dm < 8; dm++) {
      f32x4 v = acc[dm] * inv;
      *(f32x4*)(orow + dm * 16 + lg * 4) = v;
    }
  } else {
    float* pb = part + ((size_t)batch * PIECES + r) * 8192;
    int ql = w * 16 + lr;
#pragma unroll
    for (int dm = 0; dm < 8; dm++)
      *(f32x4*)(pb + ql * 128 + dm * 16 + lg * 4) = acc[dm];
    if (lg == 0) {
      float2* ml = (float2*)partml + ((size_t)batch * PIECES + r) * 64;
      ml[ql] = make_float2(m_run, l_run);
    }
  }
}

// ---------------- kernel 3: combine partials for j>=8 ----------------------
__global__ __launch_bounds__(256)
void attn_combine(const float* __restrict__ part, const float* __restrict__ partml,
                  float* __restrict__ out) {
  const int batch = blockIdx.x;
  const int j = 8 + blockIdx.y;
  int pfx = 0;
  for (int jj = 0; jj < j; jj++) pfx += (jj >> 3) + 1;
  const int P = (j >> 3) + 1;
  const int tid = threadIdx.x;
  const int ql = tid >> 2, d0 = (tid & 3) * 32;

  const float2* mlb = (const float2*)partml + ((size_t)batch * PIECES + pfx) * 64 + ql;
  float M = -3.0e38f;
  for (int p = 0; p < P; p++) M = fmaxf(M, mlb[p * 64].x);
  float L = 0.f;
  f32x4 o[8];
#pragma unroll
  for (int u = 0; u < 8; u++) o[u] = {0.f, 0.f, 0.f, 0.f};
  for (int p = 0; p < P; p++) {
    float2 ml = mlb[p * 64];
    float wgt = exp2f(ml.x - M);
    L += wgt * ml.y;
    const float* pb = part + ((size_t)batch * PIECES + pfx + p) * 8192 + ql * 128 + d0;
#pragma unroll
    for (int u = 0; u < 8; u++) o[u] += wgt * *(const f32x4*)(pb + u * 4);
  }
  const float inv = 1.f / L;
  float* orow = out + ((size_t)batch * NT + j * 64 + ql) * NH + d0;
#pragma unroll
  for (int u = 0; u < 8; u++) *(f32x4*)(orow + u * 4) = o[u] * inv;
}

// ---------------- launch ----------------------------------------------------
extern "C" void kernel_launch(void* const* d_in, const int* in_sizes, int n_in,
                              void* d_out, int out_size, void* d_ws, size_t ws_size,
                              hipStream_t stream) {
  const float* x = (const float*)d_in[0];
  const float* Wq = (const float*)d_in[1];
  const float* bq = (const float*)d_in[2];
  const float* Wk = (const float*)d_in[3];
  const float* bk = (const float*)d_in[4];
  const float* Wv = (const float*)d_in[5];
  const float* bv = (const float*)d_in[6];
  float* out = (float*)d_out;

  char* ws = (char*)d_ws;
  short* Wt = (short*)ws;                                  // 786,432 B
  short* Qb = (short*)(ws + 786432);                       // 4 MiB
  short* Kb = (short*)(ws + 786432 + 4194304);             // 4 MiB
  short* Vtb = (short*)(ws + 786432 + 2 * 4194304);        // 4 MiB
  float* part = (float*)(ws + 13369344);                   // 8*80*8192*4 = 20,971,520 B
  float* partml = (float*)(ws + 13369344 + 20971520);      // 327,680 B  (total ~33 MiB)

  wt_kernel<<<dim3(16, 2, 3), dim3(256), 0, stream>>>(Wq, Wk, Wv, Wt);
  proj_kernel<<<dim3(3, 128), dim3(256), 0, stream>>>(x, Wt, bq, bk, bv, Qb, Kb, Vtb);
  attn_partial<<<dim3(8, PIECES), dim3(256), 0, stream>>>(Qb, Kb, Vtb, out, part, partml);
  attn_combine<<<dim3(8, 24), dim3(256), 0, stream>>>(part, partml, out);
}

// Round 5
// 177.148 us; speedup vs baseline: 1.2497x; 1.1662x over previous
//
#include <hip/hip_runtime.h>
#include <hip/hip_bf16.h>
#include <math.h>

typedef __attribute__((ext_vector_type(4))) float f32x4;
typedef __attribute__((ext_vector_type(8))) short s16x8;
typedef __attribute__((ext_vector_type(4))) short s16x4;

#define NB 8
#define NT 2048
#define NC 1024
#define NH 128
// log2(e)/sqrt(C) folded into Q at projection time (exp2-domain softmax)
#define QSCALE 0.04508422002778f
#define PIECES 80   // per batch: sum_j ceil((j+1)/8), j=0..31 (KVCHUNK=512, qtile=64)

__device__ __forceinline__ short f2bf(float f) {
  __hip_bfloat16 h = __float2bfloat16(f);
  union { __hip_bfloat16 h; short s; } u; u.h = h;
  return u.s;
}

__device__ __forceinline__ void glds16(const short* g, short* l) {
  __builtin_amdgcn_global_load_lds(
      (const __attribute__((address_space(1))) unsigned int*)g,
      (__attribute__((address_space(3))) unsigned int*)l, 16, 0, 0);
}

// ---------------- kernel 0: W [C][H] fp32 -> Wt [3][H][C] bf16 --------------
__global__ __launch_bounds__(256)
void wt_kernel(const float* __restrict__ Wq, const float* __restrict__ Wk,
               const float* __restrict__ Wv, short* __restrict__ Wt) {
  __shared__ short T[64 * 72];
  const int tid = threadIdx.x;
  const int k0 = blockIdx.x * 64, n0 = blockIdx.y * 64, proj = blockIdx.z;
  const float* W = (proj == 0) ? Wq : ((proj == 1) ? Wk : Wv);
#pragma unroll
  for (int u = 0; u < 4; u++) {
    int row = u * 16 + (tid >> 4);
    int col4 = (tid & 15) * 4;
    float4 v = *(const float4*)(W + (size_t)(k0 + row) * NH + n0 + col4);
    T[(col4 + 0) * 72 + row] = f2bf(v.x);
    T[(col4 + 1) * 72 + row] = f2bf(v.y);
    T[(col4 + 2) * 72 + row] = f2bf(v.z);
    T[(col4 + 3) * 72 + row] = f2bf(v.w);
  }
  __syncthreads();
#pragma unroll
  for (int u = 0; u < 2; u++) {
    int c = tid + 256 * u;
    int n = c >> 3, c8 = c & 7;
    s16x8 v = *(const s16x8*)(T + n * 72 + c8 * 8);
    *(s16x8*)(Wt + (size_t)proj * (NH * NC) + (size_t)(n0 + n) * NC + k0 + c8 * 8) = v;
  }
}

// ---------------- kernel 1: QKV projection, M-tile 64, 768 blocks ----------
// grid (3 projs, 256 m-tiles) = 3 blocks/CU. 4 waves (2M x 2N), wave=32x64.
// LDS double-buffered: A[64][64] + B[128][64] bf16 per buf (48 KiB total).
// B via global_load_lds w/ source-XOR-swizzle; A: load-early (float4 regs),
// cvt+swizzled-ds_write late (T14). One barrier per k-step.
__global__ __launch_bounds__(256, 3)
void proj_kernel(const float* __restrict__ x, const short* __restrict__ Wt,
                 const float* __restrict__ bq, const float* __restrict__ bk,
                 const float* __restrict__ bv,
                 short* __restrict__ Qb, short* __restrict__ Kb, short* __restrict__ Vtb) {
  __shared__ __align__(16) short smem[2 * 12288];  // per buf: A 4096 + B 8192 shorts

  const int tid = threadIdx.x;
  const int w = tid >> 6, lane = tid & 63;
  const int lr = lane & 15, lg = lane >> 4;
  const int proj = blockIdx.x;
  const int m0 = blockIdx.y * 64;
  const int msub = (w & 1) * 32, nsub = (w >> 1) * 64;

  const short* Wtp = Wt + (size_t)proj * (NH * NC);
  // A prefetch: thread t covers row t>>2, float cols (t&3)*16 .. +16
  const int arow = tid >> 2, aq = tid & 3;
  const float* asrc = x + (size_t)(m0 + arow) * NC + aq * 16;

  f32x4 acc[2][4];
#pragma unroll
  for (int i = 0; i < 2; i++)
#pragma unroll
    for (int j = 0; j < 4; j++) acc[i][j] = {0.f, 0.f, 0.f, 0.f};

  float4 pa[2][4];

  auto loadA = [&](int slot, int k0) {
#pragma unroll
    for (int u = 0; u < 4; u++) pa[slot][u] = *(const float4*)(asrc + k0 + u * 4);
  };
  auto writeA = [&](int slot, int buf) {
    short* As = smem + buf * 12288;
#pragma unroll
    for (int h = 0; h < 2; h++) {
      float4 a = pa[slot][2 * h], b2 = pa[slot][2 * h + 1];
      s16x8 v;
      v[0] = f2bf(a.x); v[1] = f2bf(a.y); v[2] = f2bf(a.z); v[3] = f2bf(a.w);
      v[4] = f2bf(b2.x); v[5] = f2bf(b2.y); v[6] = f2bf(b2.z); v[7] = f2bf(b2.w);
      int cc = aq * 2 + h;
      *(s16x8*)(As + arow * 64 + ((cc ^ (arow & 7)) * 8)) = v;
    }
  };
  auto stageB = [&](int buf, int k0) {
    short* Bs = smem + buf * 12288 + 4096;
#pragma unroll
    for (int u = 0; u < 4; u++) {
      int c = u * 256 + w * 64 + lane;       // 0..1023 chunks
      int n = c >> 3, ch = c & 7;
      glds16(Wtp + (size_t)n * NC + k0 + ((ch ^ (n & 7)) * 8),
             Bs + (u * 256 + w * 64) * 8);   // wave-uniform base + lane*16
    }
  };
  auto compute = [&](int buf) {
    const short* As = smem + buf * 12288;
    const short* Bs = smem + buf * 12288 + 4096;
#pragma unroll
    for (int kc = 0; kc < 2; kc++) {
      s16x8 af[2], bf[4];
#pragma unroll
      for (int mi = 0; mi < 2; mi++) {
        int row = msub + mi * 16 + lr;
        af[mi] = *(const s16x8*)(As + row * 64 + (((kc * 4 + lg) ^ (row & 7)) * 8));
      }
#pragma unroll
      for (int ni = 0; ni < 4; ni++) {
        int row = nsub + ni * 16 + lr;
        bf[ni] = *(const s16x8*)(Bs + row * 64 + (((kc * 4 + lg) ^ (row & 7)) * 8));
      }
#pragma unroll
      for (int mi = 0; mi < 2; mi++)
#pragma unroll
        for (int ni = 0; ni < 4; ni++)
          acc[mi][ni] = __builtin_amdgcn_mfma_f32_16x16x32_bf16(af[mi], bf[ni], acc[mi][ni], 0, 0, 0);
    }
  };

  // prologue
  loadA(0, 0);
  stageB(0, 0);
  writeA(0, 0);
  __syncthreads();

  for (int s = 0; s < 16; ++s) {
    int buf = s & 1;
    int slot = (s + 1) & 1;
    if (s < 15) { loadA(slot, (s + 1) * 64); stageB(buf ^ 1, (s + 1) * 64); }
    compute(buf);
    if (s < 15) writeA(slot, buf ^ 1);
    __syncthreads();
  }

  const float* bias = (proj == 0) ? bq : ((proj == 1) ? bk : bv);
  const float scl = (proj == 0) ? QSCALE : 1.0f;
  short* Tr = smem;

  if (proj < 2) {
    // Tr[t][d] t<64 stride 136 -> coalesced row-major write
#pragma unroll
    for (int mi = 0; mi < 2; mi++)
#pragma unroll
      for (int ni = 0; ni < 4; ni++) {
        int d = nsub + ni * 16 + lr;
        float bn = bias[d];
#pragma unroll
        for (int r = 0; r < 4; r++) {
          int t = msub + mi * 16 + lg * 4 + r;
          Tr[t * 136 + d] = f2bf((acc[mi][ni][r] + bn) * scl);
        }
      }
    __syncthreads();
    short* dst = (proj == 0) ? Qb : Kb;
#pragma unroll
    for (int i = 0; i < 4; i++) {
      int c = tid + 256 * i;  // 0..1023
      int t = c >> 4, cc = c & 15;
      s16x8 v = *(const s16x8*)(Tr + t * 136 + cc * 8);
      *(s16x8*)(dst + (size_t)(m0 + t) * NH + cc * 8) = v;
    }
  } else {
    // Tr2[d][t] d<128 stride 72 -> Vt[b][d][t]
#pragma unroll
    for (int mi = 0; mi < 2; mi++)
#pragma unroll
      for (int ni = 0; ni < 4; ni++) {
        int d = nsub + ni * 16 + lr;
        float bn = bias[d];
        int t0 = msub + mi * 16 + lg * 4;
        s16x4 v;
        v[0] = f2bf(acc[mi][ni][0] + bn);
        v[1] = f2bf(acc[mi][ni][1] + bn);
        v[2] = f2bf(acc[mi][ni][2] + bn);
        v[3] = f2bf(acc[mi][ni][3] + bn);
        *(s16x4*)(Tr + d * 72 + t0) = v;
      }
    __syncthreads();
    int b = m0 >> 11, t0g = m0 & 2047;
#pragma unroll
    for (int i = 0; i < 4; i++) {
      int c = tid + 256 * i;  // 0..1023
      int d = c >> 3, cc = c & 7;
      s16x8 v = *(const s16x8*)(Tr + d * 72 + cc * 8);
      *(s16x8*)(Vtb + (size_t)b * (NH * NT) + (size_t)d * NT + t0g + cc * 8) = v;
    }
  }
}

// ---------------- kernel 2: split-KV flash attention partials --------------
// grid (8 batches, 80 pieces). KVSTEP=64 double-buffered (64 KiB LDS):
// 32 MFMA + one softmax pass per barrier. K[64][128] and V[128][64] tiles
// staged via global_load_lds with source-XOR swizzle (chunk ^= row&7).
__global__ __launch_bounds__(256, 2)
void attn_partial(const short* __restrict__ Qb, const short* __restrict__ Kb,
                  const short* __restrict__ Vtb, float* __restrict__ out,
                  float* __restrict__ part, float* __restrict__ partml) {
  __shared__ __align__(16) short smem[32768];  // K[2][64][128] @0, V[2][128][64] @16384

  const int tid = threadIdx.x;
  const int w = tid >> 6, lane = tid & 63;
  const int lr = lane & 15, lg = lane >> 4;

  const int batch = blockIdx.x;
  const int r = (PIECES - 1) - blockIdx.y;  // heavy pieces first
  int j = 0, pfx = 0;
  while (pfx + (j >> 3) + 1 <= r) { pfx += (j >> 3) + 1; j++; }
  const int c = r - pfx;
  const int P = (j >> 3) + 1;
  const int q0 = j * 64;
  const int kv_begin = c * 512;
  const int kv_end = min(kv_begin + 512, (j + 1) * 64);
  const int nsteps = (kv_end - kv_begin) >> 6;

  const short* Kp = Kb + (size_t)batch * NT * NH;
  const short* Vp = Vtb + (size_t)batch * NH * NT;
  const int q = q0 + w * 16 + lr;

  const short* Qrow = Qb + (size_t)(batch * NT + q) * NH;
  s16x8 qf[4];
#pragma unroll
  for (int dc = 0; dc < 4; dc++) qf[dc] = *(const s16x8*)(Qrow + dc * 32 + lg * 8);

  f32x4 acc[8];
#pragma unroll
  for (int i = 0; i < 8; i++) acc[i] = {0.f, 0.f, 0.f, 0.f};
  float m_run = -3.0e38f, l_run = 0.f;

  auto stage = [&](int buf, int kv0) {
#pragma unroll
    for (int u = 0; u < 4; u++) {  // K tile [64][128]: 1024 chunks
      int c2 = u * 256 + w * 64 + lane;
      int row = c2 >> 4, ch = c2 & 15;
      int sch = (ch & 8) | ((ch & 7) ^ (row & 7));
      glds16(Kp + (size_t)(kv0 + row) * NH + sch * 8,
             smem + buf * 8192 + (u * 256 + w * 64) * 8);
    }
#pragma unroll
    for (int u = 0; u < 4; u++) {  // V tile [128][64]: 1024 chunks
      int c2 = u * 256 + w * 64 + lane;
      int d = c2 >> 3, ch = c2 & 7;
      int sch = ch ^ (d & 7);
      glds16(Vp + (size_t)d * NT + kv0 + sch * 8,
             smem + 16384 + buf * 8192 + (u * 256 + w * 64) * 8);
    }
  };

  stage(0, kv_begin);
  __syncthreads();

  for (int s = 0; s < nsteps; s++) {
    const int buf = s & 1;
    const int kv0 = kv_begin + s * 64;
    if (s + 1 < nsteps) stage(buf ^ 1, kv0 + 64);

    const short* Kl = smem + buf * 8192;
    const short* Vl = smem + 16384 + buf * 8192;

    f32x4 st[4];
#pragma unroll
    for (int sub = 0; sub < 4; sub++) st[sub] = {0.f, 0.f, 0.f, 0.f};
#pragma unroll
    for (int dc = 0; dc < 4; dc++) {
      int ch = dc * 4 + lg;
      int sch = (ch & 8) | ((ch & 7) ^ (lr & 7));
#pragma unroll
      for (int sub = 0; sub < 4; sub++) {
        s16x8 kf = *(const s16x8*)(Kl + (sub * 16 + lr) * 128 + sch * 8);
        st[sub] = __builtin_amdgcn_mfma_f32_16x16x32_bf16(kf, qf[dc], st[sub], 0, 0, 0);
      }
    }
    if (kv0 + 63 > q0) {  // diagonal: causal mask
#pragma unroll
      for (int sub = 0; sub < 4; sub++)
#pragma unroll
        for (int rr = 0; rr < 4; rr++)
          if (kv0 + sub * 16 + lg * 4 + rr > q) st[sub][rr] = -3.0e38f;
    }
    float tm = -3.0e38f;
#pragma unroll
    for (int sub = 0; sub < 4; sub++)
#pragma unroll
      for (int rr = 0; rr < 4; rr++) tm = fmaxf(tm, st[sub][rr]);
    tm = fmaxf(tm, __shfl_xor(tm, 16, 64));
    tm = fmaxf(tm, __shfl_xor(tm, 32, 64));
    float m_new = fmaxf(m_run, tm);
    float corr = exp2f(m_run - m_new);
    float psum = 0.f;
    s16x8 pf[2];
#pragma unroll
    for (int sub = 0; sub < 4; sub++)
#pragma unroll
      for (int rr = 0; rr < 4; rr++) {
        float p = exp2f(st[sub][rr] - m_new);
        psum += p;
        pf[sub >> 1][(sub & 1) * 4 + rr] = f2bf(p);
      }
    psum += __shfl_xor(psum, 16, 64);
    psum += __shfl_xor(psum, 32, 64);
    l_run = l_run * corr + psum;
    m_run = m_new;
#pragma unroll
    for (int i = 0; i < 8; i++) acc[i] *= corr;
    // PV: k-slot layout matches st/pf ownership (permuted slots, no shuffle)
#pragma unroll
    for (int ks = 0; ks < 2; ks++)
#pragma unroll
      for (int dm = 0; dm < 8; dm++) {
        int d = dm * 16 + lr;
        const short* vb = Vl + d * 64;
        int ch0 = (ks * 4 + (lg >> 1)) ^ (d & 7);
        int ch1 = ch0 ^ 2;
        s16x4 v0 = *(const s16x4*)(vb + ch0 * 8 + (lg & 1) * 4);
        s16x4 v1 = *(const s16x4*)(vb + ch1 * 8 + (lg & 1) * 4);
        s16x8 vf = __builtin_shufflevector(v0, v1, 0, 1, 2, 3, 4, 5, 6, 7);
        acc[dm] = __builtin_amdgcn_mfma_f32_16x16x32_bf16(vf, pf[ks], acc[dm], 0, 0, 0);
      }
    __syncthreads();
  }

  if (P == 1) {
    const float inv = 1.f / l_run;
    float* orow = out + (size_t)(batch * NT + q) * NH;
#pragma unroll
    for (int dm = 0; dm < 8; dm++) {
      f32x4 v = acc[dm] * inv;
      *(f32x4*)(orow + dm * 16 + lg * 4) = v;
    }
  } else {
    float* pb = part + ((size_t)batch * PIECES + r) * 8192;
    int ql = w * 16 + lr;
#pragma unroll
    for (int dm = 0; dm < 8; dm++)
      *(f32x4*)(pb + ql * 128 + dm * 16 + lg * 4) = acc[dm];
    if (lg == 0) {
      float2* ml = (float2*)partml + ((size_t)batch * PIECES + r) * 64;
      ml[ql] = make_float2(m_run, l_run);
    }
  }
}

// ---------------- kernel 3: combine partials for j>=8 ----------------------
__global__ __launch_bounds__(256)
void attn_combine(const float* __restrict__ part, const float* __restrict__ partml,
                  float* __restrict__ out) {
  const int batch = blockIdx.x;
  const int j = 8 + blockIdx.y;
  int pfx = 0;
  for (int jj = 0; jj < j; jj++) pfx += (jj >> 3) + 1;
  const int P = (j >> 3) + 1;
  const int tid = threadIdx.x;
  const int ql = tid >> 2, d0 = (tid & 3) * 32;

  const float2* mlb = (const float2*)partml + ((size_t)batch * PIECES + pfx) * 64 + ql;
  float M = -3.0e38f;
  for (int p = 0; p < P; p++) M = fmaxf(M, mlb[p * 64].x);
  float L = 0.f;
  f32x4 o[8];
#pragma unroll
  for (int u = 0; u < 8; u++) o[u] = {0.f, 0.f, 0.f, 0.f};
  for (int p = 0; p < P; p++) {
    float2 ml = mlb[p * 64];
    float wgt = exp2f(ml.x - M);
    L += wgt * ml.y;
    const float* pb = part + ((size_t)batch * PIECES + pfx + p) * 8192 + ql * 128 + d0;
#pragma unroll
    for (int u = 0; u < 8; u++) o[u] += wgt * *(const f32x4*)(pb + u * 4);
  }
  const float inv = 1.f / L;
  float* orow = out + ((size_t)batch * NT + j * 64 + ql) * NH + d0;
#pragma unroll
  for (int u = 0; u < 8; u++) *(f32x4*)(orow + u * 4) = o[u] * inv;
}

// ---------------- launch ----------------------------------------------------
extern "C" void kernel_launch(void* const* d_in, const int* in_sizes, int n_in,
                              void* d_out, int out_size, void* d_ws, size_t ws_size,
                              hipStream_t stream) {
  const float* x = (const float*)d_in[0];
  const float* Wq = (const float*)d_in[1];
  const float* bq = (const float*)d_in[2];
  const float* Wk = (const float*)d_in[3];
  const float* bk = (const float*)d_in[4];
  const float* Wv = (const float*)d_in[5];
  const float* bv = (const float*)d_in[6];
  float* out = (float*)d_out;

  char* ws = (char*)d_ws;
  short* Wt = (short*)ws;                                  // 786,432 B
  short* Qb = (short*)(ws + 786432);                       // 4 MiB
  short* Kb = (short*)(ws + 786432 + 4194304);             // 4 MiB
  short* Vtb = (short*)(ws + 786432 + 2 * 4194304);        // 4 MiB
  float* part = (float*)(ws + 13369344);                   // 20,971,520 B
  float* partml = (float*)(ws + 13369344 + 20971520);      // 327,680 B (total ~33 MiB)

  wt_kernel<<<dim3(16, 2, 3), dim3(256), 0, stream>>>(Wq, Wk, Wv, Wt);
  proj_kernel<<<dim3(3, 256), dim3(256), 0, stream>>>(x, Wt, bq, bk, bv, Qb, Kb, Vtb);
  attn_partial<<<dim3(8, PIECES), dim3(256), 0, stream>>>(Qb, Kb, Vtb, out, part, partml);
  attn_combine<<<dim3(8, 24), dim3(256), 0, stream>>>(part, partml, out);
}